// Round 16
// baseline (301.977 us; speedup 1.0000x reference)
//
#include <hip/hip_runtime.h>
#include <hip/hip_bf16.h>

typedef __bf16 bf16x8 __attribute__((ext_vector_type(8)));
typedef float f32x4 __attribute__((ext_vector_type(4)));
typedef float f32x16 __attribute__((ext_vector_type(16)));
typedef unsigned int uint;
typedef unsigned short u16;

#define DEV static __device__ __forceinline__

DEV u16 f2bf(float x) {
    uint u = __builtin_bit_cast(uint, x);
    u += 0x7FFFu + ((u >> 16) & 1u);
    return (u16)(u >> 16);
}

DEV uint cvtpk(float lo, float hi) {
    uint r;
    asm("v_cvt_pk_bf16_f32 %0, %1, %2" : "=v"(r) : "v"(lo), "v"(hi));
    return r;
}

DEV void plswap(uint& a, uint& b) {
    asm("v_permlane32_swap_b32 %0, %1" : "+v"(a), "+v"(b));
}

DEV float fexp2(float x) { return __builtin_amdgcn_exp2f(x); }

DEV void gload16(const void* g, void* l) {
    __builtin_amdgcn_global_load_lds((const __attribute__((address_space(1))) void*)g,
                                     (__attribute__((address_space(3))) void*)l,
                                     16, 0, 0);
}

// ---------------- all-4-weights fp32 -> bf16, one launch ---------------------
__global__ __launch_bounds__(256) void k_wconv(const float* __restrict__ w0,
                                               const float* __restrict__ w1,
                                               const float* __restrict__ w2,
                                               const float* __restrict__ w3,
                                               u16* __restrict__ out) {
    const int which = blockIdx.x >> 9;
    const float* in = which == 0 ? w0 : (which == 1 ? w1 : (which == 2 ? w2 : w3));
    const long i = (blockIdx.x & 511) * 256 + threadIdx.x;
    const float4* p = (const float4*)in + i * 2;
    float4 a = p[0], b = p[1];
    uint4 dv;
    dv.x = cvtpk(a.x, a.y); dv.y = cvtpk(a.z, a.w);
    dv.z = cvtpk(b.x, b.y); dv.w = cvtpk(b.z, b.w);
    ((uint4*)(out + ((long)which << 20)))[i] = dv;
}

// ---------------- fused QKV GEMM: A fp32 direct global->reg, B via LDS -------
// A fragments loaded per-lane from global (L2/L3-hot, cache-line aligned per
// (row,kc) across lk lanes), cvtpk at use. LDS stages ONLY B (16KB/step).
// Barrier schedule identical to k_gemm_bt. seg0 Q (pre-scaled by
// 0.125*log2(e)), seg1 K, seg2 V -> V^T via LDS-bounce epilogue.
__global__ __launch_bounds__(256, 2) void k_gemm_qkv(
    const float* __restrict__ Aq, const float* __restrict__ Ak,
    const float* __restrict__ Av, const u16* __restrict__ Bw,
    const float* __restrict__ b0, const float* __restrict__ b1,
    const float* __restrict__ b2, u16* __restrict__ Cb,
    u16* __restrict__ VT) {
    constexpr int N = 1024, K = 1024;
    __shared__ u16 lS[16384];          // 32KB: B tile [0,16K); epilogue uses all
    const int tid = threadIdx.x;
    const int l = tid & 63, w = tid >> 6;
    const int lr = l & 15, lk = l >> 4;
    const int wr = w >> 1, wc = w & 1;
    const int nbn = N >> 7;
    const int cpx = (int)gridDim.x >> 3;
    const int wg = (blockIdx.x & 7) * cpx + (blockIdx.x >> 3);
    const int bm = wg / nbn, bn = wg % nbn;
    const int seg = bm >> 6;
    const float* Aseg = seg == 0 ? Aq : (seg == 1 ? Ak : Av);
    const u16* Bseg = Bw + ((long)seg << 20);
    const float* bias = seg == 0 ? b0 : (seg == 1 ? b1 : b2);
    const int bml = bm & 63;
    const float oscale = seg == 0 ? 0.18033688f : 1.0f;

    // A: per-lane row pointers (4 m-frags); frag cols kt*64 + kc*32 + lk*8
    const float* arow[4];
#pragma unroll
    for (int m = 0; m < 4; ++m)
        arow[m] = Aseg + (long)(bml * 128 + wr * 64 + m * 16 + lr) * 1024 + lk * 8;

    // B staging: 4 chunks/thread; bf16 rows of 128B, 3-bit swizzle (as bt)
    long bbase[4];
    int bdst[4];
#pragma unroll
    for (int t = 0; t < 4; ++t) {
        int p = (t * 256 + tid) * 16;
        int row = p >> 7;
        int src = (p & 127) ^ ((row & 7) << 4);
        bdst[t] = p;
        bbase[t] = (long)(bn * 128 + row) * (K * 2) + src;
    }
    const int swz = (lr & 7) << 4;
    int boff[4][2];
#pragma unroll
    for (int n = 0; n < 4; ++n)
#pragma unroll
        for (int kc = 0; kc < 2; ++kc)
            boff[n][kc] = (wc * 64 + n * 16 + lr) * 128 + ((kc * 64 + lk * 16) ^ swz);

    f32x4 acc[4][4] = {};
    const char* gB = (const char*)Bseg;
    const char* lBb = (const char*)lS;
    for (int kt = 0; kt < K / 64; ++kt) {
        __syncthreads();                      // prev reads of lS done
#pragma unroll
        for (int t = 0; t < 4; ++t)
            gload16(gB + bbase[t] + kt * 128, (char*)lS + bdst[t]);
        // A fragment loads direct to regs (issued alongside B staging)
        f32x4 a[4][2][2];
#pragma unroll
        for (int m = 0; m < 4; ++m)
#pragma unroll
            for (int kc = 0; kc < 2; ++kc) {
                const float* p = arow[m] + kt * 64 + kc * 32;
                a[m][kc][0] = *(const f32x4*)p;
                a[m][kc][1] = *(const f32x4*)(p + 4);
            }
        __syncthreads();                      // drains vmcnt: B in LDS, A in regs
#pragma unroll
        for (int kc = 0; kc < 2; ++kc) {
            bf16x8 av[4], bv[4];
#pragma unroll
            for (int m = 0; m < 4; ++m) {
                union { uint u[4]; bf16x8 v; } af;
                af.u[0] = cvtpk(a[m][kc][0].x, a[m][kc][0].y);
                af.u[1] = cvtpk(a[m][kc][0].z, a[m][kc][0].w);
                af.u[2] = cvtpk(a[m][kc][1].x, a[m][kc][1].y);
                af.u[3] = cvtpk(a[m][kc][1].z, a[m][kc][1].w);
                av[m] = af.v;
            }
#pragma unroll
            for (int n = 0; n < 4; ++n) bv[n] = *(const bf16x8*)(lBb + boff[n][kc]);
#pragma unroll
            for (int m = 0; m < 4; ++m)
#pragma unroll
                for (int n = 0; n < 4; ++n)
                    acc[m][n] = __builtin_amdgcn_mfma_f32_16x16x32_bf16(av[m], bv[n], acc[m][n], 0, 0, 0);
        }
    }

    const int col0 = bn * 128 + wc * 64;
    float bval[4];
#pragma unroll
    for (int n = 0; n < 4; ++n) bval[n] = bias[col0 + n * 16 + lr];

    if (seg < 2) {
        const int row0 = bm * 128 + wr * 64;
#pragma unroll
        for (int m = 0; m < 4; ++m)
#pragma unroll
            for (int j = 0; j < 4; ++j) {
                int row = row0 + m * 16 + lk * 4 + j;
#pragma unroll
                for (int n = 0; n < 4; ++n)
                    Cb[(long)row * N + col0 + n * 16 + lr] =
                        f2bf((acc[m][n][j] + bval[n]) * oscale);
            }
    } else {
        // LDS-transpose epilogue: [token 128][channel 128] -> lS[channel][token]
        __syncthreads();   // all waves done reading lS (B tile)
#pragma unroll
        for (int m = 0; m < 4; ++m)
#pragma unroll
            for (int j = 0; j < 4; ++j) {
                int row = wr * 64 + m * 16 + lk * 4 + j;        // local token
#pragma unroll
                for (int n = 0; n < 4; ++n) {
                    int col = wc * 64 + n * 16 + lr;            // local channel
                    *(u16*)((char*)lS + col * 256 + ((row * 2) ^ ((col & 7) << 4))) =
                        f2bf(acc[m][n][j] + bval[n]);
                }
            }
        __syncthreads();
        const int bb = bml >> 4;
        const int t0 = (bml & 15) * 128;
        const int c = tid >> 4;
        const int chunk = tid & 15;
#pragma unroll
        for (int pass = 0; pass < 8; ++pass) {
            int cc = pass * 16 + c;
            uint4 val = *(const uint4*)((const char*)lS + cc * 256 +
                                        ((chunk * 16) ^ ((cc & 7) << 4)));
            int gcol = bn * 128 + cc;
            int hh = gcol >> 6, dh = gcol & 63;
            *(uint4*)((char*)VT +
                      ((((long)(bb * 16 + hh) * 64 + dh) << 11) + t0 + chunk * 8) * 2) = val;
        }
    }
}

// ---------------- bf16 GEMM (Wo projection), fp32 out ------------------------
__global__ __launch_bounds__(256, 2) void k_gemm_bt(
    const u16* __restrict__ A, const u16* __restrict__ Bw,
    const float* __restrict__ bias, float* __restrict__ Cf,
    int M, int N, int K) {
    __shared__ u16 lA[128 * 64];
    __shared__ u16 lB[128 * 64];
    const int tid = threadIdx.x;
    const int l = tid & 63, w = tid >> 6;
    const int lr = l & 15, lk = l >> 4;
    const int wr = w >> 1, wc = w & 1;
    const int nbn = N >> 7;
    const int cpx = (int)gridDim.x >> 3;
    const int wg = (blockIdx.x & 7) * cpx + (blockIdx.x >> 3);
    const int bm = wg / nbn, bn = wg % nbn;

    long abase[4], bbase[4];
    int ldst[4];
#pragma unroll
    for (int t = 0; t < 4; ++t) {
        int c = t * 256 + tid;
        int p = c * 16;
        int row = p >> 7;
        int inrow = p & 127;
        int src = inrow ^ ((row & 7) << 4);
        ldst[t] = p;
        abase[t] = (long)(bm * 128 + row) * (K * 2) + src;
        bbase[t] = (long)(bn * 128 + row) * (K * 2) + src;
    }
    const int swz = (lr & 7) << 4;
    int aoff[4][2], boff[4][2];
#pragma unroll
    for (int m = 0; m < 4; ++m)
#pragma unroll
        for (int kc = 0; kc < 2; ++kc) {
            aoff[m][kc] = (wr * 64 + m * 16 + lr) * 128 + ((kc * 64 + lk * 16) ^ swz);
            boff[m][kc] = (wc * 64 + m * 16 + lr) * 128 + ((kc * 64 + lk * 16) ^ swz);
        }

    f32x4 acc[4][4] = {};
    const char* gA = (const char*)A;
    const char* gB = (const char*)Bw;
    const char* lAb = (const char*)lA;
    const char* lBb = (const char*)lB;
    const int nkt = K >> 6;
    for (int kt = 0; kt < nkt; ++kt) {
        __syncthreads();
#pragma unroll
        for (int t = 0; t < 4; ++t)
            gload16(gA + abase[t] + kt * 128, (char*)lA + ldst[t]);
#pragma unroll
        for (int t = 0; t < 4; ++t)
            gload16(gB + bbase[t] + kt * 128, (char*)lB + ldst[t]);
        __syncthreads();
#pragma unroll
        for (int kc = 0; kc < 2; ++kc) {
            bf16x8 av[4], bv[4];
#pragma unroll
            for (int m = 0; m < 4; ++m) av[m] = *(const bf16x8*)(lAb + aoff[m][kc]);
#pragma unroll
            for (int n = 0; n < 4; ++n) bv[n] = *(const bf16x8*)(lBb + boff[n][kc]);
#pragma unroll
            for (int m = 0; m < 4; ++m)
#pragma unroll
                for (int n = 0; n < 4; ++n)
                    acc[m][n] = __builtin_amdgcn_mfma_f32_16x16x32_bf16(av[m], bv[n], acc[m][n], 0, 0, 0);
        }
    }

    const int row0 = bm * 128 + wr * 64;
    const int col0 = bn * 128 + wc * 64;
    float bval[4];
#pragma unroll
    for (int n = 0; n < 4; ++n) bval[n] = bias[col0 + n * 16 + lr];
#pragma unroll
    for (int m = 0; m < 4; ++m)
#pragma unroll
        for (int j = 0; j < 4; ++j) {
            int row = row0 + m * 16 + lk * 4 + j;
#pragma unroll
            for (int n = 0; n < 4; ++n)
                Cf[(long)row * N + col0 + n * 16 + lr] = acc[m][n][j] + bval[n];
        }
}

// ---------------- flash attention v7: KVBLK=128, VALU rowsum (r13) -----------
__global__ __launch_bounds__(512, 4) void k_attn7(
    const u16* __restrict__ Qb, const u16* __restrict__ Kb,
    const u16* __restrict__ VTb, u16* __restrict__ Ob) {
    constexpr int T = 2048, D = 1024;
    constexpr int NT2 = T / 128;
    __shared__ u16 sK[2][8192];
    __shared__ u16 sV[2][8192];
    const int tid = threadIdx.x;
    const int l = tid & 63, w = tid >> 6;
    const int hi = l >> 5;
    const int q32 = l & 31;
    const int hi16 = hi * 16;
    const int kswz = (q32 & 7) << 4;
    const int bid = blockIdx.x;
    const int bh = (bid & 7) * 8 + ((bid >> 3) & 7);
    const int qt = bid >> 6;
    const int b = bh >> 4, h = bh & 15;

    const char* Qg = (const char*)(Qb + (long)b * T * D + h * 64);
    const char* Kg = (const char*)(Kb + (long)b * T * D + h * 64);
    const char* VTg = (const char*)(VTb + (long)bh * 64 * 2048);
    const int q0 = qt * 256 + w * 32;

    bf16x8 qf[4];
#pragma unroll
    for (int c = 0; c < 4; ++c)
        qf[c] = *(const bf16x8*)(Qg + (long)(q0 + q32) * 2048 + c * 32 + hi16);

    long kbase[2], vbase[2];
    int sdst[2];
#pragma unroll
    for (int t = 0; t < 2; ++t) {
        int id = tid + t * 512;
        sdst[t] = id * 16;
        int kr = id >> 3, kp = (id & 7) * 16;
        kbase[t] = (long)kr * 2048 + (kp ^ ((kr & 7) << 4));
        int vr = id >> 4, vp = (id & 15) * 16;
        vbase[t] = (long)vr * 4096 + (vp ^ ((vr & 7) << 4));
    }

#define STAGE2(kt_, buf_) do {                                                  \
        long kb = (long)(kt_) * 128 * 2048;                                     \
        gload16(Kg + kb + kbase[0], (char*)sK[buf_] + sdst[0]);                 \
        gload16(Kg + kb + kbase[1], (char*)sK[buf_] + sdst[1]);                 \
        gload16(VTg + (kt_) * 256 + vbase[0], (char*)sV[buf_] + sdst[0]);       \
        gload16(VTg + (kt_) * 256 + vbase[1], (char*)sV[buf_] + sdst[1]);       \
    } while (0)

    STAGE2(0, 0);
    __syncthreads();

    f32x16 o[2] = {};
    float ls0 = 0.f, ls1 = 0.f, ls2 = 0.f, ls3 = 0.f;

    for (int kt = 0; kt < NT2; ++kt) {
        if (kt + 1 < NT2) STAGE2(kt + 1, (kt + 1) & 1);

        const char* kbp = (const char*)sK[kt & 1];
        const char* vbp = (const char*)sV[kt & 1];
#pragma unroll
        for (int half = 0; half < 2; ++half) {
            f32x16 st[2] = {};
            __builtin_amdgcn_s_setprio(1);
#pragma unroll
            for (int c = 0; c < 4; ++c) {
                bf16x8 kf = *(const bf16x8*)(kbp + (half * 64 + q32) * 128 +
                                             ((c * 32 + hi16) ^ kswz));
                st[0] = __builtin_amdgcn_mfma_f32_32x32x16_bf16(kf, qf[c], st[0], 0, 0, 0);
            }
#pragma unroll
            for (int c = 0; c < 4; ++c) {
                bf16x8 kf = *(const bf16x8*)(kbp + (half * 64 + 32 + q32) * 128 +
                                             ((c * 32 + hi16) ^ kswz));
                st[1] = __builtin_amdgcn_mfma_f32_32x32x16_bf16(kf, qf[c], st[1], 0, 0, 0);
            }
            __builtin_amdgcn_s_setprio(0);

#pragma unroll
            for (int n = 0; n < 2; ++n)
#pragma unroll
                for (int r = 0; r < 16; ++r) {
                    float p = fexp2(st[n][r]);
                    st[n][r] = p;
                    if ((r & 3) == 0) ls0 += p;
                    else if ((r & 3) == 1) ls1 += p;
                    else if ((r & 3) == 2) ls2 += p;
                    else ls3 += p;
                }

            __builtin_amdgcn_s_setprio(1);
#pragma unroll
            for (int c = 0; c < 4; ++c) {
                const int n = c >> 1, rb = (c & 1) * 8;
                uint A0 = cvtpk(st[n][rb + 0], st[n][rb + 1]);
                uint A1 = cvtpk(st[n][rb + 2], st[n][rb + 3]);
                uint B0 = cvtpk(st[n][rb + 4], st[n][rb + 5]);
                uint B1 = cvtpk(st[n][rb + 6], st[n][rb + 7]);
                plswap(A0, B0);
                plswap(A1, B1);
                union { uint u[4]; bf16x8 v; } pa;
                pa.u[0] = A0; pa.u[1] = A1; pa.u[2] = B0; pa.u[3] = B1;
                int cb = (c * 32 + hi16) ^ kswz;
                bf16x8 v0 = *(const bf16x8*)(vbp + q32 * 256 + half * 128 + cb);
                bf16x8 v1 = *(const bf16x8*)(vbp + (32 + q32) * 256 + half * 128 + cb);
                o[0] = __builtin_amdgcn_mfma_f32_32x32x16_bf16(pa.v, v0, o[0], 0, 0, 0);
                o[1] = __builtin_amdgcn_mfma_f32_32x32x16_bf16(pa.v, v1, o[1], 0, 0, 0);
            }
            __builtin_amdgcn_s_setprio(0);
        }
        __syncthreads();
    }
#undef STAGE2

    float lsum = (ls0 + ls1) + (ls2 + ls3);
    float total = lsum + __shfl_xor(lsum, 32);
#pragma unroll
    for (int r = 0; r < 16; ++r) {
        int srcq = (r & 3) + 8 * (r >> 2) + 4 * hi;
        float inv = 1.f / __shfl(total, srcq);
        int trow = q0 + srcq;
        char* orow = (char*)Ob + ((long)(b * T + trow) * D + h * 64) * 2;
        *(u16*)(orow + q32 * 2) = f2bf(o[0][r] * inv);
        *(u16*)(orow + (32 + q32) * 2) = f2bf(o[1][r] * inv);
    }
}

// ---------------------------------------------------------------------------
extern "C" void kernel_launch(void* const* d_in, const int* in_sizes, int n_in,
                              void* d_out, int out_size, void* d_ws, size_t ws_size,
                              hipStream_t stream) {
    const float* q  = (const float*)d_in[0];
    const float* k  = (const float*)d_in[1];
    const float* v  = (const float*)d_in[2];
    const float* Wq = (const float*)d_in[3];
    const float* bq = (const float*)d_in[4];
    const float* Wk = (const float*)d_in[5];
    const float* bk = (const float*)d_in[6];
    const float* Wv = (const float*)d_in[7];
    const float* bv = (const float*)d_in[8];
    const float* Wo = (const float*)d_in[9];
    const float* bo = (const float*)d_in[10];

    const long MT = 8192L * 1024;
    const long WT = 1024L * 1024;
    u16* ws   = (u16*)d_ws;
    u16* wall = ws;                    // Wq|Wk|Wv|Wo bf16, stacked
    u16* qbf  = wall + 4 * WT;         // Q (pre-scaled) | K row-major
    u16* kbf  = qbf + MT;
    u16* vtb  = kbf + MT;              // V^T [bh][dh][t]
    u16* abf  = vtb + MT;              // attention output

    k_wconv<<<dim3(2048), dim3(256), 0, stream>>>(Wq, Wk, Wv, Wo, wall);

    k_gemm_qkv<<<dim3(1536), dim3(256), 0, stream>>>(q, k, v, wall,
                                                     bq, bk, bv, qbf, vtb);

    k_attn7<<<dim3(512), dim3(512), 0, stream>>>(qbf, kbf, vtb, abf);

    k_gemm_bt<<<dim3(512), dim3(256), 0, stream>>>(abf, wall + 3 * WT, bo,
                                                   (float*)d_out, 8192, 1024, 1024);
}

// Round 17
// 192.828 us; speedup vs baseline: 1.5660x; 1.5660x over previous
//
#include <hip/hip_runtime.h>
#include <hip/hip_bf16.h>

typedef __bf16 bf16x8 __attribute__((ext_vector_type(8)));
typedef float f32x4 __attribute__((ext_vector_type(4)));
typedef float f32x16 __attribute__((ext_vector_type(16)));
typedef unsigned int uint;
typedef unsigned short u16;

#define DEV static __device__ __forceinline__

DEV u16 f2bf(float x) {
    uint u = __builtin_bit_cast(uint, x);
    u += 0x7FFFu + ((u >> 16) & 1u);
    return (u16)(u >> 16);
}

DEV uint cvtpk(float lo, float hi) {
    uint r;
    asm("v_cvt_pk_bf16_f32 %0, %1, %2" : "=v"(r) : "v"(lo), "v"(hi));
    return r;
}

DEV void plswap(uint& a, uint& b) {
    asm("v_permlane32_swap_b32 %0, %1" : "+v"(a), "+v"(b));
}

DEV float fexp2(float x) { return __builtin_amdgcn_exp2f(x); }

DEV void gload16(const void* g, void* l) {
    __builtin_amdgcn_global_load_lds((const __attribute__((address_space(1))) void*)g,
                                     (__attribute__((address_space(3))) void*)l,
                                     16, 0, 0);
}

// ---------------- all-4-weights fp32 -> bf16, one launch ---------------------
__global__ __launch_bounds__(256) void k_wconv(const float* __restrict__ w0,
                                               const float* __restrict__ w1,
                                               const float* __restrict__ w2,
                                               const float* __restrict__ w3,
                                               u16* __restrict__ out) {
    const int which = blockIdx.x >> 9;
    const float* in = which == 0 ? w0 : (which == 1 ? w1 : (which == 2 ? w2 : w3));
    const long i = (blockIdx.x & 511) * 256 + threadIdx.x;
    const float4* p = (const float4*)in + i * 2;
    float4 a = p[0], b = p[1];
    uint4 dv;
    dv.x = cvtpk(a.x, a.y); dv.y = cvtpk(a.z, a.w);
    dv.z = cvtpk(b.x, b.y); dv.w = cvtpk(b.z, b.w);
    ((uint4*)(out + ((long)which << 20)))[i] = dv;
}

// ---------------- fused QKV GEMM (r14): fp32 A via global_load_lds -----------
// A staged RAW fp32 into LDS (32KB tile, pre-swizzled source); fp32->bf16 at
// fragment-read (2x ds_read_b128 + 4 cvtpk), overlapped with MFMA.
// seg0 Q (pre-scaled by 0.125*log2(e)), seg1 K, seg2 V -> V^T LDS-bounce.
__global__ __launch_bounds__(256, 2) void k_gemm_qkv(
    const float* __restrict__ Aq, const float* __restrict__ Ak,
    const float* __restrict__ Av, const u16* __restrict__ Bw,
    const float* __restrict__ b0, const float* __restrict__ b1,
    const float* __restrict__ b2, u16* __restrict__ Cb,
    u16* __restrict__ VT) {
    constexpr int N = 1024, K = 1024;
    __shared__ u16 lS[24576];          // 48KB: A fp32 [0,32K), B bf16 [32K,48K)
    const int tid = threadIdx.x;
    const int l = tid & 63, w = tid >> 6;
    const int lr = l & 15, lk = l >> 4;
    const int wr = w >> 1, wc = w & 1;
    const int nbn = N >> 7;
    const int cpx = (int)gridDim.x >> 3;
    const int wg = (blockIdx.x & 7) * cpx + (blockIdx.x >> 3);
    const int bm = wg / nbn, bn = wg % nbn;
    const int seg = bm >> 6;
    const float* Aseg = seg == 0 ? Aq : (seg == 1 ? Ak : Av);
    const u16* Bseg = Bw + ((long)seg << 20);
    const float* bias = seg == 0 ? b0 : (seg == 1 ? b1 : b2);
    const int bml = bm & 63;
    const float oscale = seg == 0 ? 0.18033688f : 1.0f;

    long abase[8];
    int adst[8];
#pragma unroll
    for (int t = 0; t < 8; ++t) {
        int id = t * 256 + tid;
        int row = id >> 4;
        int p = (id & 15) * 16;
        int src = p ^ ((row & 15) << 4);
        adst[t] = id * 16;
        abase[t] = (long)(bml * 128 + row) * 4096 + src;
    }
    long bbase[4];
    int bdst[4];
#pragma unroll
    for (int t = 0; t < 4; ++t) {
        int p = (t * 256 + tid) * 16;
        int row = p >> 7;
        int src = (p & 127) ^ ((row & 7) << 4);
        bdst[t] = p;
        bbase[t] = (long)(bn * 128 + row) * (K * 2) + src;
    }
    const int swz = (lr & 7) << 4;
    int aoff[4][2], boff[4][2];
#pragma unroll
    for (int m = 0; m < 4; ++m)
#pragma unroll
        for (int kc = 0; kc < 2; ++kc) {
            aoff[m][kc] = (wr * 64 + m * 16 + lr) * 256 + ((kc * 128 + lk * 32) ^ (lr << 4));
            boff[m][kc] = (wc * 64 + m * 16 + lr) * 128 + ((kc * 64 + lk * 16) ^ swz);
        }

    f32x4 acc[4][4] = {};
    const char* gA = (const char*)Aseg;
    const char* gB = (const char*)Bseg;
    const char* lAb = (const char*)lS;
    const char* lBb = (const char*)lS + 32768;
    for (int kt = 0; kt < K / 64; ++kt) {
        __syncthreads();
#pragma unroll
        for (int t = 0; t < 8; ++t)
            gload16(gA + abase[t] + kt * 256, (char*)lS + adst[t]);
#pragma unroll
        for (int t = 0; t < 4; ++t)
            gload16(gB + bbase[t] + kt * 128, (char*)lS + 32768 + bdst[t]);
        __syncthreads();
#pragma unroll
        for (int kc = 0; kc < 2; ++kc) {
            bf16x8 av[4], bv[4];
#pragma unroll
            for (int m = 0; m < 4; ++m) {
                f32x4 a0 = *(const f32x4*)(lAb + aoff[m][kc]);
                f32x4 a1 = *(const f32x4*)(lAb + (aoff[m][kc] ^ 16));
                union { uint u[4]; bf16x8 v; } af;
                af.u[0] = cvtpk(a0.x, a0.y);
                af.u[1] = cvtpk(a0.z, a0.w);
                af.u[2] = cvtpk(a1.x, a1.y);
                af.u[3] = cvtpk(a1.z, a1.w);
                av[m] = af.v;
            }
#pragma unroll
            for (int n = 0; n < 4; ++n) bv[n] = *(const bf16x8*)(lBb + boff[n][kc]);
#pragma unroll
            for (int m = 0; m < 4; ++m)
#pragma unroll
                for (int n = 0; n < 4; ++n)
                    acc[m][n] = __builtin_amdgcn_mfma_f32_16x16x32_bf16(av[m], bv[n], acc[m][n], 0, 0, 0);
        }
    }

    const int col0 = bn * 128 + wc * 64;
    float bval[4];
#pragma unroll
    for (int n = 0; n < 4; ++n) bval[n] = bias[col0 + n * 16 + lr];

    if (seg < 2) {
        const int row0 = bm * 128 + wr * 64;
#pragma unroll
        for (int m = 0; m < 4; ++m)
#pragma unroll
            for (int j = 0; j < 4; ++j) {
                int row = row0 + m * 16 + lk * 4 + j;
#pragma unroll
                for (int n = 0; n < 4; ++n)
                    Cb[(long)row * N + col0 + n * 16 + lr] =
                        f2bf((acc[m][n][j] + bval[n]) * oscale);
            }
    } else {
        __syncthreads();
#pragma unroll
        for (int m = 0; m < 4; ++m)
#pragma unroll
            for (int j = 0; j < 4; ++j) {
                int row = wr * 64 + m * 16 + lk * 4 + j;
#pragma unroll
                for (int n = 0; n < 4; ++n) {
                    int col = wc * 64 + n * 16 + lr;
                    *(u16*)((char*)lS + col * 256 + ((row * 2) ^ ((col & 7) << 4))) =
                        f2bf(acc[m][n][j] + bval[n]);
                }
            }
        __syncthreads();
        const int bb = bml >> 4;
        const int t0 = (bml & 15) * 128;
        const int c = tid >> 4;
        const int chunk = tid & 15;
#pragma unroll
        for (int pass = 0; pass < 8; ++pass) {
            int cc = pass * 16 + c;
            uint4 val = *(const uint4*)((const char*)lS + cc * 256 +
                                        ((chunk * 16) ^ ((cc & 7) << 4)));
            int gcol = bn * 128 + cc;
            int hh = gcol >> 6, dh = gcol & 63;
            *(uint4*)((char*)VT +
                      ((((long)(bb * 16 + hh) * 64 + dh) << 11) + t0 + chunk * 8) * 2) = val;
        }
    }
}

// ---------------- bf16 GEMM (Wo projection), fp32 out ------------------------
__global__ __launch_bounds__(256, 2) void k_gemm_bt(
    const u16* __restrict__ A, const u16* __restrict__ Bw,
    const float* __restrict__ bias, float* __restrict__ Cf,
    int M, int N, int K) {
    __shared__ u16 lA[128 * 64];
    __shared__ u16 lB[128 * 64];
    const int tid = threadIdx.x;
    const int l = tid & 63, w = tid >> 6;
    const int lr = l & 15, lk = l >> 4;
    const int wr = w >> 1, wc = w & 1;
    const int nbn = N >> 7;
    const int cpx = (int)gridDim.x >> 3;
    const int wg = (blockIdx.x & 7) * cpx + (blockIdx.x >> 3);
    const int bm = wg / nbn, bn = wg % nbn;

    long abase[4], bbase[4];
    int ldst[4];
#pragma unroll
    for (int t = 0; t < 4; ++t) {
        int c = t * 256 + tid;
        int p = c * 16;
        int row = p >> 7;
        int inrow = p & 127;
        int src = inrow ^ ((row & 7) << 4);
        ldst[t] = p;
        abase[t] = (long)(bm * 128 + row) * (K * 2) + src;
        bbase[t] = (long)(bn * 128 + row) * (K * 2) + src;
    }
    const int swz = (lr & 7) << 4;
    int aoff[4][2], boff[4][2];
#pragma unroll
    for (int m = 0; m < 4; ++m)
#pragma unroll
        for (int kc = 0; kc < 2; ++kc) {
            aoff[m][kc] = (wr * 64 + m * 16 + lr) * 128 + ((kc * 64 + lk * 16) ^ swz);
            boff[m][kc] = (wc * 64 + m * 16 + lr) * 128 + ((kc * 64 + lk * 16) ^ swz);
        }

    f32x4 acc[4][4] = {};
    const char* gA = (const char*)A;
    const char* gB = (const char*)Bw;
    const char* lAb = (const char*)lA;
    const char* lBb = (const char*)lB;
    const int nkt = K >> 6;
    for (int kt = 0; kt < nkt; ++kt) {
        __syncthreads();
#pragma unroll
        for (int t = 0; t < 4; ++t)
            gload16(gA + abase[t] + kt * 128, (char*)lA + ldst[t]);
#pragma unroll
        for (int t = 0; t < 4; ++t)
            gload16(gB + bbase[t] + kt * 128, (char*)lB + ldst[t]);
        __syncthreads();
#pragma unroll
        for (int kc = 0; kc < 2; ++kc) {
            bf16x8 av[4], bv[4];
#pragma unroll
            for (int m = 0; m < 4; ++m) av[m] = *(const bf16x8*)(lAb + aoff[m][kc]);
#pragma unroll
            for (int n = 0; n < 4; ++n) bv[n] = *(const bf16x8*)(lBb + boff[n][kc]);
#pragma unroll
            for (int m = 0; m < 4; ++m)
#pragma unroll
                for (int n = 0; n < 4; ++n)
                    acc[m][n] = __builtin_amdgcn_mfma_f32_16x16x32_bf16(av[m], bv[n], acc[m][n], 0, 0, 0);
        }
    }

    const int row0 = bm * 128 + wr * 64;
    const int col0 = bn * 128 + wc * 64;
    float bval[4];
#pragma unroll
    for (int n = 0; n < 4; ++n) bval[n] = bias[col0 + n * 16 + lr];
#pragma unroll
    for (int m = 0; m < 4; ++m)
#pragma unroll
        for (int j = 0; j < 4; ++j) {
            int row = row0 + m * 16 + lk * 4 + j;
#pragma unroll
            for (int n = 0; n < 4; ++n)
                Cf[(long)row * N + col0 + n * 16 + lr] = acc[m][n][j] + bval[n];
        }
}

// ---------------- flash attention v8: 2-stage pipeline across halves ---------
// Per 128-kv tile: QK(h0) -> exp+compress(h0)->pa0 -> QK(h1) -> PV(h0) ->
// exp+compress(h1) -> PV(h1). QK(h1) fills MFMA pipe under exp(h0); PV(h0)
// covers exp(h1)'s dependency window. pa compression caps VGPR (+16 only).
__global__ __launch_bounds__(512, 4) void k_attn8(
    const u16* __restrict__ Qb, const u16* __restrict__ Kb,
    const u16* __restrict__ VTb, u16* __restrict__ Ob) {
    constexpr int T = 2048, D = 1024;
    constexpr int NT2 = T / 128;
    __shared__ u16 sK[2][8192];
    __shared__ u16 sV[2][8192];
    const int tid = threadIdx.x;
    const int l = tid & 63, w = tid >> 6;
    const int hi = l >> 5;
    const int q32 = l & 31;
    const int hi16 = hi * 16;
    const int kswz = (q32 & 7) << 4;
    const int bid = blockIdx.x;
    const int bh = (bid & 7) * 8 + ((bid >> 3) & 7);
    const int qt = bid >> 6;
    const int b = bh >> 4, h = bh & 15;

    const char* Qg = (const char*)(Qb + (long)b * T * D + h * 64);
    const char* Kg = (const char*)(Kb + (long)b * T * D + h * 64);
    const char* VTg = (const char*)(VTb + (long)bh * 64 * 2048);
    const int q0 = qt * 256 + w * 32;

    bf16x8 qf[4];
#pragma unroll
    for (int c = 0; c < 4; ++c)
        qf[c] = *(const bf16x8*)(Qg + (long)(q0 + q32) * 2048 + c * 32 + hi16);

    long kbase[2], vbase[2];
    int sdst[2];
#pragma unroll
    for (int t = 0; t < 2; ++t) {
        int id = tid + t * 512;
        sdst[t] = id * 16;
        int kr = id >> 3, kp = (id & 7) * 16;
        kbase[t] = (long)kr * 2048 + (kp ^ ((kr & 7) << 4));
        int vr = id >> 4, vp = (id & 15) * 16;
        vbase[t] = (long)vr * 4096 + (vp ^ ((vr & 7) << 4));
    }

#define STAGE2(kt_, buf_) do {                                                  \
        long kb = (long)(kt_) * 128 * 2048;                                     \
        gload16(Kg + kb + kbase[0], (char*)sK[buf_] + sdst[0]);                 \
        gload16(Kg + kb + kbase[1], (char*)sK[buf_] + sdst[1]);                 \
        gload16(VTg + (kt_) * 256 + vbase[0], (char*)sV[buf_] + sdst[0]);       \
        gload16(VTg + (kt_) * 256 + vbase[1], (char*)sV[buf_] + sdst[1]);       \
    } while (0)

// QK for one half into st[2]
#define QKHALF(half_, stv)                                                      \
    do {                                                                        \
        __builtin_amdgcn_s_setprio(1);                                          \
        _Pragma("unroll")                                                       \
        for (int c = 0; c < 4; ++c) {                                           \
            bf16x8 kf = *(const bf16x8*)(kbp + ((half_) * 64 + q32) * 128 +     \
                                         ((c * 32 + hi16) ^ kswz));             \
            stv[0] = __builtin_amdgcn_mfma_f32_32x32x16_bf16(kf, qf[c], stv[0], 0, 0, 0); \
        }                                                                       \
        _Pragma("unroll")                                                       \
        for (int c = 0; c < 4; ++c) {                                           \
            bf16x8 kf = *(const bf16x8*)(kbp + ((half_) * 64 + 32 + q32) * 128 +\
                                         ((c * 32 + hi16) ^ kswz));             \
            stv[1] = __builtin_amdgcn_mfma_f32_32x32x16_bf16(kf, qf[c], stv[1], 0, 0, 0); \
        }                                                                       \
        __builtin_amdgcn_s_setprio(0);                                          \
    } while (0)

// exp2 + rowsum partials + compress to bf16 A-frags
#define EXPCVT(stv, pav)                                                        \
    do {                                                                        \
        _Pragma("unroll")                                                       \
        for (int n = 0; n < 2; ++n)                                             \
            _Pragma("unroll")                                                   \
            for (int r = 0; r < 16; ++r) {                                      \
                float p = fexp2(stv[n][r]);                                     \
                stv[n][r] = p;                                                  \
                if ((r & 3) == 0) ls0 += p;                                     \
                else if ((r & 3) == 1) ls1 += p;                                \
                else if ((r & 3) == 2) ls2 += p;                                \
                else ls3 += p;                                                  \
            }                                                                   \
        _Pragma("unroll")                                                       \
        for (int c = 0; c < 4; ++c) {                                           \
            const int n = c >> 1, rb = (c & 1) * 8;                             \
            uint A0 = cvtpk(stv[n][rb + 0], stv[n][rb + 1]);                    \
            uint A1 = cvtpk(stv[n][rb + 2], stv[n][rb + 3]);                    \
            uint B0 = cvtpk(stv[n][rb + 4], stv[n][rb + 5]);                    \
            uint B1 = cvtpk(stv[n][rb + 6], stv[n][rb + 7]);                    \
            plswap(A0, B0);                                                     \
            plswap(A1, B1);                                                     \
            union { uint u[4]; bf16x8 v; } pk_;                                 \
            pk_.u[0] = A0; pk_.u[1] = A1; pk_.u[2] = B0; pk_.u[3] = B1;         \
            pav[c] = pk_.v;                                                     \
        }                                                                       \
    } while (0)

#define PVHALF(half_, pav)                                                      \
    do {                                                                        \
        __builtin_amdgcn_s_setprio(1);                                          \
        _Pragma("unroll")                                                       \
        for (int c = 0; c < 4; ++c) {                                           \
            int cb = (c * 32 + hi16) ^ kswz;                                    \
            bf16x8 v0 = *(const bf16x8*)(vbp + q32 * 256 + (half_) * 128 + cb); \
            bf16x8 v1 = *(const bf16x8*)(vbp + (32 + q32) * 256 + (half_) * 128 + cb); \
            o[0] = __builtin_amdgcn_mfma_f32_32x32x16_bf16(pav[c], v0, o[0], 0, 0, 0); \
            o[1] = __builtin_amdgcn_mfma_f32_32x32x16_bf16(pav[c], v1, o[1], 0, 0, 0); \
        }                                                                       \
        __builtin_amdgcn_s_setprio(0);                                          \
    } while (0)

    STAGE2(0, 0);
    __syncthreads();

    f32x16 o[2] = {};
    float ls0 = 0.f, ls1 = 0.f, ls2 = 0.f, ls3 = 0.f;

    for (int kt = 0; kt < NT2; ++kt) {
        if (kt + 1 < NT2) STAGE2(kt + 1, (kt + 1) & 1);

        const char* kbp = (const char*)sK[kt & 1];
        const char* vbp = (const char*)sV[kt & 1];

        f32x16 st0[2] = {};
        QKHALF(0, st0);
        bf16x8 pa0[4];
        EXPCVT(st0, pa0);               // TRANS/VALU; overlaps with ...
        f32x16 st1[2] = {};
        QKHALF(1, st1);                 // ... these MFMAs (independent)
        PVHALF(0, pa0);                 // MFMA; overlaps exp(h1) window
        bf16x8 pa1[4];
        EXPCVT(st1, pa1);
        PVHALF(1, pa1);
        __syncthreads();
    }
#undef STAGE2
#undef QKHALF
#undef EXPCVT
#undef PVHALF

    float lsum = (ls0 + ls1) + (ls2 + ls3);
    float total = lsum + __shfl_xor(lsum, 32);
#pragma unroll
    for (int r = 0; r < 16; ++r) {
        int srcq = (r & 3) + 8 * (r >> 2) + 4 * hi;
        float inv = 1.f / __shfl(total, srcq);
        int trow = q0 + srcq;
        char* orow = (char*)Ob + ((long)(b * T + trow) * D + h * 64) * 2;
        *(u16*)(orow + q32 * 2) = f2bf(o[0][r] * inv);
        *(u16*)(orow + (32 + q32) * 2) = f2bf(o[1][r] * inv);
    }
}

// ---------------------------------------------------------------------------
extern "C" void kernel_launch(void* const* d_in, const int* in_sizes, int n_in,
                              void* d_out, int out_size, void* d_ws, size_t ws_size,
                              hipStream_t stream) {
    const float* q  = (const float*)d_in[0];
    const float* k  = (const float*)d_in[1];
    const float* v  = (const float*)d_in[2];
    const float* Wq = (const float*)d_in[3];
    const float* bq = (const float*)d_in[4];
    const float* Wk = (const float*)d_in[5];
    const float* bk = (const float*)d_in[6];
    const float* Wv = (const float*)d_in[7];
    const float* bv = (const float*)d_in[8];
    const float* Wo = (const float*)d_in[9];
    const float* bo = (const float*)d_in[10];

    const long MT = 8192L * 1024;
    const long WT = 1024L * 1024;
    u16* ws   = (u16*)d_ws;
    u16* wall = ws;                    // Wq|Wk|Wv|Wo bf16, stacked
    u16* qbf  = wall + 4 * WT;         // Q (pre-scaled) | K row-major
    u16* kbf  = qbf + MT;
    u16* vtb  = kbf + MT;              // V^T [bh][dh][t]
    u16* abf  = vtb + MT;              // attention output

    k_wconv<<<dim3(2048), dim3(256), 0, stream>>>(Wq, Wk, Wv, Wo, wall);

    k_gemm_qkv<<<dim3(1536), dim3(256), 0, stream>>>(q, k, v, wall,
                                                     bq, bk, bv, qbf, vtb);

    k_attn8<<<dim3(512), dim3(512), 0, stream>>>(qbf, kbf, vtb, abf);

    k_gemm_bt<<<dim3(512), dim3(256), 0, stream>>>(abf, wall + 3 * WT, bo,
                                                   (float*)d_out, 8192, 1024, 1024);
}

// Round 18
// 177.505 us; speedup vs baseline: 1.7012x; 1.0863x over previous
//
#include <hip/hip_runtime.h>
#include <hip/hip_bf16.h>

typedef __bf16 bf16x8 __attribute__((ext_vector_type(8)));
typedef float f32x4 __attribute__((ext_vector_type(4)));
typedef float f32x16 __attribute__((ext_vector_type(16)));
typedef unsigned int uint;
typedef unsigned short u16;

#define DEV static __device__ __forceinline__

DEV u16 f2bf(float x) {
    uint u = __builtin_bit_cast(uint, x);
    u += 0x7FFFu + ((u >> 16) & 1u);
    return (u16)(u >> 16);
}

DEV uint cvtpk(float lo, float hi) {
    uint r;
    asm("v_cvt_pk_bf16_f32 %0, %1, %2" : "=v"(r) : "v"(lo), "v"(hi));
    return r;
}

DEV void plswap(uint& a, uint& b) {
    asm("v_permlane32_swap_b32 %0, %1" : "+v"(a), "+v"(b));
}

DEV float fexp2(float x) { return __builtin_amdgcn_exp2f(x); }

DEV void gload16(const void* g, void* l) {
    __builtin_amdgcn_global_load_lds((const __attribute__((address_space(1))) void*)g,
                                     (__attribute__((address_space(3))) void*)l,
                                     16, 0, 0);
}

// ---------------- all-4-weights fp32 -> bf16, one launch ---------------------
__global__ __launch_bounds__(256) void k_wconv(const float* __restrict__ w0,
                                               const float* __restrict__ w1,
                                               const float* __restrict__ w2,
                                               const float* __restrict__ w3,
                                               u16* __restrict__ out) {
    const int which = blockIdx.x >> 9;
    const float* in = which == 0 ? w0 : (which == 1 ? w1 : (which == 2 ? w2 : w3));
    const long i = (blockIdx.x & 511) * 256 + threadIdx.x;
    const float4* p = (const float4*)in + i * 2;
    float4 a = p[0], b = p[1];
    uint4 dv;
    dv.x = cvtpk(a.x, a.y); dv.y = cvtpk(a.z, a.w);
    dv.z = cvtpk(b.x, b.y); dv.w = cvtpk(b.z, b.w);
    ((uint4*)(out + ((long)which << 20)))[i] = dv;
}

// ---------------- fused QKV GEMM (r14-best): fp32 A via global_load_lds ------
// A staged RAW fp32 into LDS (32KB tile, pre-swizzled source); fp32->bf16 at
// fragment-read (2x ds_read_b128 + 4 cvtpk), overlapped with MFMA.
// seg0 Q (pre-scaled by 0.125*log2(e)), seg1 K, seg2 V -> V^T LDS-bounce.
__global__ __launch_bounds__(256, 2) void k_gemm_qkv(
    const float* __restrict__ Aq, const float* __restrict__ Ak,
    const float* __restrict__ Av, const u16* __restrict__ Bw,
    const float* __restrict__ b0, const float* __restrict__ b1,
    const float* __restrict__ b2, u16* __restrict__ Cb,
    u16* __restrict__ VT) {
    constexpr int N = 1024, K = 1024;
    __shared__ u16 lS[24576];          // 48KB: A fp32 [0,32K), B bf16 [32K,48K)
    const int tid = threadIdx.x;
    const int l = tid & 63, w = tid >> 6;
    const int lr = l & 15, lk = l >> 4;
    const int wr = w >> 1, wc = w & 1;
    const int nbn = N >> 7;
    const int cpx = (int)gridDim.x >> 3;
    const int wg = (blockIdx.x & 7) * cpx + (blockIdx.x >> 3);
    const int bm = wg / nbn, bn = wg % nbn;
    const int seg = bm >> 6;
    const float* Aseg = seg == 0 ? Aq : (seg == 1 ? Ak : Av);
    const u16* Bseg = Bw + ((long)seg << 20);
    const float* bias = seg == 0 ? b0 : (seg == 1 ? b1 : b2);
    const int bml = bm & 63;
    const float oscale = seg == 0 ? 0.18033688f : 1.0f;

    long abase[8];
    int adst[8];
#pragma unroll
    for (int t = 0; t < 8; ++t) {
        int id = t * 256 + tid;
        int row = id >> 4;
        int p = (id & 15) * 16;
        int src = p ^ ((row & 15) << 4);
        adst[t] = id * 16;
        abase[t] = (long)(bml * 128 + row) * 4096 + src;
    }
    long bbase[4];
    int bdst[4];
#pragma unroll
    for (int t = 0; t < 4; ++t) {
        int p = (t * 256 + tid) * 16;
        int row = p >> 7;
        int src = (p & 127) ^ ((row & 7) << 4);
        bdst[t] = p;
        bbase[t] = (long)(bn * 128 + row) * (K * 2) + src;
    }
    const int swz = (lr & 7) << 4;
    int aoff[4][2], boff[4][2];
#pragma unroll
    for (int m = 0; m < 4; ++m)
#pragma unroll
        for (int kc = 0; kc < 2; ++kc) {
            aoff[m][kc] = (wr * 64 + m * 16 + lr) * 256 + ((kc * 128 + lk * 32) ^ (lr << 4));
            boff[m][kc] = (wc * 64 + m * 16 + lr) * 128 + ((kc * 64 + lk * 16) ^ swz);
        }

    f32x4 acc[4][4] = {};
    const char* gA = (const char*)Aseg;
    const char* gB = (const char*)Bseg;
    const char* lAb = (const char*)lS;
    const char* lBb = (const char*)lS + 32768;
    for (int kt = 0; kt < K / 64; ++kt) {
        __syncthreads();
#pragma unroll
        for (int t = 0; t < 8; ++t)
            gload16(gA + abase[t] + kt * 256, (char*)lS + adst[t]);
#pragma unroll
        for (int t = 0; t < 4; ++t)
            gload16(gB + bbase[t] + kt * 128, (char*)lS + 32768 + bdst[t]);
        __syncthreads();
#pragma unroll
        for (int kc = 0; kc < 2; ++kc) {
            bf16x8 av[4], bv[4];
#pragma unroll
            for (int m = 0; m < 4; ++m) {
                f32x4 a0 = *(const f32x4*)(lAb + aoff[m][kc]);
                f32x4 a1 = *(const f32x4*)(lAb + (aoff[m][kc] ^ 16));
                union { uint u[4]; bf16x8 v; } af;
                af.u[0] = cvtpk(a0.x, a0.y);
                af.u[1] = cvtpk(a0.z, a0.w);
                af.u[2] = cvtpk(a1.x, a1.y);
                af.u[3] = cvtpk(a1.z, a1.w);
                av[m] = af.v;
            }
#pragma unroll
            for (int n = 0; n < 4; ++n) bv[n] = *(const bf16x8*)(lBb + boff[n][kc]);
#pragma unroll
            for (int m = 0; m < 4; ++m)
#pragma unroll
                for (int n = 0; n < 4; ++n)
                    acc[m][n] = __builtin_amdgcn_mfma_f32_16x16x32_bf16(av[m], bv[n], acc[m][n], 0, 0, 0);
        }
    }

    const int col0 = bn * 128 + wc * 64;
    float bval[4];
#pragma unroll
    for (int n = 0; n < 4; ++n) bval[n] = bias[col0 + n * 16 + lr];

    if (seg < 2) {
        const int row0 = bm * 128 + wr * 64;
#pragma unroll
        for (int m = 0; m < 4; ++m)
#pragma unroll
            for (int j = 0; j < 4; ++j) {
                int row = row0 + m * 16 + lk * 4 + j;
#pragma unroll
                for (int n = 0; n < 4; ++n)
                    Cb[(long)row * N + col0 + n * 16 + lr] =
                        f2bf((acc[m][n][j] + bval[n]) * oscale);
            }
    } else {
        __syncthreads();
#pragma unroll
        for (int m = 0; m < 4; ++m)
#pragma unroll
            for (int j = 0; j < 4; ++j) {
                int row = wr * 64 + m * 16 + lk * 4 + j;
#pragma unroll
                for (int n = 0; n < 4; ++n) {
                    int col = wc * 64 + n * 16 + lr;
                    *(u16*)((char*)lS + col * 256 + ((row * 2) ^ ((col & 7) << 4))) =
                        f2bf(acc[m][n][j] + bval[n]);
                }
            }
        __syncthreads();
        const int bb = bml >> 4;
        const int t0 = (bml & 15) * 128;
        const int c = tid >> 4;
        const int chunk = tid & 15;
#pragma unroll
        for (int pass = 0; pass < 8; ++pass) {
            int cc = pass * 16 + c;
            uint4 val = *(const uint4*)((const char*)lS + cc * 256 +
                                        ((chunk * 16) ^ ((cc & 7) << 4)));
            int gcol = bn * 128 + cc;
            int hh = gcol >> 6, dh = gcol & 63;
            *(uint4*)((char*)VT +
                      ((((long)(bb * 16 + hh) * 64 + dh) << 11) + t0 + chunk * 8) * 2) = val;
        }
    }
}

// ---------------- bf16 GEMM (Wo projection), fp32 out ------------------------
__global__ __launch_bounds__(256, 2) void k_gemm_bt(
    const u16* __restrict__ A, const u16* __restrict__ Bw,
    const float* __restrict__ bias, float* __restrict__ Cf,
    int M, int N, int K) {
    __shared__ u16 lA[128 * 64];
    __shared__ u16 lB[128 * 64];
    const int tid = threadIdx.x;
    const int l = tid & 63, w = tid >> 6;
    const int lr = l & 15, lk = l >> 4;
    const int wr = w >> 1, wc = w & 1;
    const int nbn = N >> 7;
    const int cpx = (int)gridDim.x >> 3;
    const int wg = (blockIdx.x & 7) * cpx + (blockIdx.x >> 3);
    const int bm = wg / nbn, bn = wg % nbn;

    long abase[4], bbase[4];
    int ldst[4];
#pragma unroll
    for (int t = 0; t < 4; ++t) {
        int c = t * 256 + tid;
        int p = c * 16;
        int row = p >> 7;
        int inrow = p & 127;
        int src = inrow ^ ((row & 7) << 4);
        ldst[t] = p;
        abase[t] = (long)(bm * 128 + row) * (K * 2) + src;
        bbase[t] = (long)(bn * 128 + row) * (K * 2) + src;
    }
    const int swz = (lr & 7) << 4;
    int aoff[4][2], boff[4][2];
#pragma unroll
    for (int m = 0; m < 4; ++m)
#pragma unroll
        for (int kc = 0; kc < 2; ++kc) {
            aoff[m][kc] = (wr * 64 + m * 16 + lr) * 128 + ((kc * 64 + lk * 16) ^ swz);
            boff[m][kc] = (wc * 64 + m * 16 + lr) * 128 + ((kc * 64 + lk * 16) ^ swz);
        }

    f32x4 acc[4][4] = {};
    const char* gA = (const char*)A;
    const char* gB = (const char*)Bw;
    const char* lAb = (const char*)lA;
    const char* lBb = (const char*)lB;
    const int nkt = K >> 6;
    for (int kt = 0; kt < nkt; ++kt) {
        __syncthreads();
#pragma unroll
        for (int t = 0; t < 4; ++t)
            gload16(gA + abase[t] + kt * 128, (char*)lA + ldst[t]);
#pragma unroll
        for (int t = 0; t < 4; ++t)
            gload16(gB + bbase[t] + kt * 128, (char*)lB + ldst[t]);
        __syncthreads();
#pragma unroll
        for (int kc = 0; kc < 2; ++kc) {
            bf16x8 av[4], bv[4];
#pragma unroll
            for (int m = 0; m < 4; ++m) av[m] = *(const bf16x8*)(lAb + aoff[m][kc]);
#pragma unroll
            for (int n = 0; n < 4; ++n) bv[n] = *(const bf16x8*)(lBb + boff[n][kc]);
#pragma unroll
            for (int m = 0; m < 4; ++m)
#pragma unroll
                for (int n = 0; n < 4; ++n)
                    acc[m][n] = __builtin_amdgcn_mfma_f32_16x16x32_bf16(av[m], bv[n], acc[m][n], 0, 0, 0);
        }
    }

    const int row0 = bm * 128 + wr * 64;
    const int col0 = bn * 128 + wc * 64;
    float bval[4];
#pragma unroll
    for (int n = 0; n < 4; ++n) bval[n] = bias[col0 + n * 16 + lr];
#pragma unroll
    for (int m = 0; m < 4; ++m)
#pragma unroll
        for (int j = 0; j < 4; ++j) {
            int row = row0 + m * 16 + lk * 4 + j;
#pragma unroll
            for (int n = 0; n < 4; ++n)
                Cf[(long)row * N + col0 + n * 16 + lr] = acc[m][n][j] + bval[n];
        }
}

// ---------------- flash attention v7 (r13/r14-best): KVBLK=128 ---------------
// Max-free softmax (Q pre-scaled), VALU rowsum, 16 barrier-iters.
__global__ __launch_bounds__(512, 4) void k_attn7(
    const u16* __restrict__ Qb, const u16* __restrict__ Kb,
    const u16* __restrict__ VTb, u16* __restrict__ Ob) {
    constexpr int T = 2048, D = 1024;
    constexpr int NT2 = T / 128;
    __shared__ u16 sK[2][8192];
    __shared__ u16 sV[2][8192];
    const int tid = threadIdx.x;
    const int l = tid & 63, w = tid >> 6;
    const int hi = l >> 5;
    const int q32 = l & 31;
    const int hi16 = hi * 16;
    const int kswz = (q32 & 7) << 4;
    const int bid = blockIdx.x;
    const int bh = (bid & 7) * 8 + ((bid >> 3) & 7);
    const int qt = bid >> 6;
    const int b = bh >> 4, h = bh & 15;

    const char* Qg = (const char*)(Qb + (long)b * T * D + h * 64);
    const char* Kg = (const char*)(Kb + (long)b * T * D + h * 64);
    const char* VTg = (const char*)(VTb + (long)bh * 64 * 2048);
    const int q0 = qt * 256 + w * 32;

    bf16x8 qf[4];
#pragma unroll
    for (int c = 0; c < 4; ++c)
        qf[c] = *(const bf16x8*)(Qg + (long)(q0 + q32) * 2048 + c * 32 + hi16);

    long kbase[2], vbase[2];
    int sdst[2];
#pragma unroll
    for (int t = 0; t < 2; ++t) {
        int id = tid + t * 512;
        sdst[t] = id * 16;
        int kr = id >> 3, kp = (id & 7) * 16;
        kbase[t] = (long)kr * 2048 + (kp ^ ((kr & 7) << 4));
        int vr = id >> 4, vp = (id & 15) * 16;
        vbase[t] = (long)vr * 4096 + (vp ^ ((vr & 7) << 4));
    }

#define STAGE2(kt_, buf_) do {                                                  \
        long kb = (long)(kt_) * 128 * 2048;                                     \
        gload16(Kg + kb + kbase[0], (char*)sK[buf_] + sdst[0]);                 \
        gload16(Kg + kb + kbase[1], (char*)sK[buf_] + sdst[1]);                 \
        gload16(VTg + (kt_) * 256 + vbase[0], (char*)sV[buf_] + sdst[0]);       \
        gload16(VTg + (kt_) * 256 + vbase[1], (char*)sV[buf_] + sdst[1]);       \
    } while (0)

    STAGE2(0, 0);
    __syncthreads();

    f32x16 o[2] = {};
    float ls0 = 0.f, ls1 = 0.f, ls2 = 0.f, ls3 = 0.f;

    for (int kt = 0; kt < NT2; ++kt) {
        if (kt + 1 < NT2) STAGE2(kt + 1, (kt + 1) & 1);

        const char* kbp = (const char*)sK[kt & 1];
        const char* vbp = (const char*)sV[kt & 1];
#pragma unroll
        for (int half = 0; half < 2; ++half) {
            f32x16 st[2] = {};
            __builtin_amdgcn_s_setprio(1);
#pragma unroll
            for (int c = 0; c < 4; ++c) {
                bf16x8 kf = *(const bf16x8*)(kbp + (half * 64 + q32) * 128 +
                                             ((c * 32 + hi16) ^ kswz));
                st[0] = __builtin_amdgcn_mfma_f32_32x32x16_bf16(kf, qf[c], st[0], 0, 0, 0);
            }
#pragma unroll
            for (int c = 0; c < 4; ++c) {
                bf16x8 kf = *(const bf16x8*)(kbp + (half * 64 + 32 + q32) * 128 +
                                             ((c * 32 + hi16) ^ kswz));
                st[1] = __builtin_amdgcn_mfma_f32_32x32x16_bf16(kf, qf[c], st[1], 0, 0, 0);
            }
            __builtin_amdgcn_s_setprio(0);

#pragma unroll
            for (int n = 0; n < 2; ++n)
#pragma unroll
                for (int r = 0; r < 16; ++r) {
                    float p = fexp2(st[n][r]);
                    st[n][r] = p;
                    if ((r & 3) == 0) ls0 += p;
                    else if ((r & 3) == 1) ls1 += p;
                    else if ((r & 3) == 2) ls2 += p;
                    else ls3 += p;
                }

            __builtin_amdgcn_s_setprio(1);
#pragma unroll
            for (int c = 0; c < 4; ++c) {
                const int n = c >> 1, rb = (c & 1) * 8;
                uint A0 = cvtpk(st[n][rb + 0], st[n][rb + 1]);
                uint A1 = cvtpk(st[n][rb + 2], st[n][rb + 3]);
                uint B0 = cvtpk(st[n][rb + 4], st[n][rb + 5]);
                uint B1 = cvtpk(st[n][rb + 6], st[n][rb + 7]);
                plswap(A0, B0);
                plswap(A1, B1);
                union { uint u[4]; bf16x8 v; } pa;
                pa.u[0] = A0; pa.u[1] = A1; pa.u[2] = B0; pa.u[3] = B1;
                int cb = (c * 32 + hi16) ^ kswz;
                bf16x8 v0 = *(const bf16x8*)(vbp + q32 * 256 + half * 128 + cb);
                bf16x8 v1 = *(const bf16x8*)(vbp + (32 + q32) * 256 + half * 128 + cb);
                o[0] = __builtin_amdgcn_mfma_f32_32x32x16_bf16(pa.v, v0, o[0], 0, 0, 0);
                o[1] = __builtin_amdgcn_mfma_f32_32x32x16_bf16(pa.v, v1, o[1], 0, 0, 0);
            }
            __builtin_amdgcn_s_setprio(0);
        }
        __syncthreads();
    }
#undef STAGE2

    float lsum = (ls0 + ls1) + (ls2 + ls3);
    float total = lsum + __shfl_xor(lsum, 32);
#pragma unroll
    for (int r = 0; r < 16; ++r) {
        int srcq = (r & 3) + 8 * (r >> 2) + 4 * hi;
        float inv = 1.f / __shfl(total, srcq);
        int trow = q0 + srcq;
        char* orow = (char*)Ob + ((long)(b * T + trow) * D + h * 64) * 2;
        *(u16*)(orow + q32 * 2) = f2bf(o[0][r] * inv);
        *(u16*)(orow + (32 + q32) * 2) = f2bf(o[1][r] * inv);
    }
}

// ---------------------------------------------------------------------------
extern "C" void kernel_launch(void* const* d_in, const int* in_sizes, int n_in,
                              void* d_out, int out_size, void* d_ws, size_t ws_size,
                              hipStream_t stream) {
    const float* q  = (const float*)d_in[0];
    const float* k  = (const float*)d_in[1];
    const float* v  = (const float*)d_in[2];
    const float* Wq = (const float*)d_in[3];
    const float* bq = (const float*)d_in[4];
    const float* Wk = (const float*)d_in[5];
    const float* bk = (const float*)d_in[6];
    const float* Wv = (const float*)d_in[7];
    const float* bv = (const float*)d_in[8];
    const float* Wo = (const float*)d_in[9];
    const float* bo = (const float*)d_in[10];

    const long MT = 8192L * 1024;
    const long WT = 1024L * 1024;
    u16* ws   = (u16*)d_ws;
    u16* wall = ws;                    // Wq|Wk|Wv|Wo bf16, stacked
    u16* qbf  = wall + 4 * WT;         // Q (pre-scaled) | K row-major
    u16* kbf  = qbf + MT;
    u16* vtb  = kbf + MT;              // V^T [bh][dh][t]
    u16* abf  = vtb + MT;              // attention output

    k_wconv<<<dim3(2048), dim3(256), 0, stream>>>(Wq, Wk, Wv, Wo, wall);

    k_gemm_qkv<<<dim3(1536), dim3(256), 0, stream>>>(q, k, v, wall,
                                                     bq, bk, bv, qbf, vtb);

    k_attn7<<<dim3(512), dim3(512), 0, stream>>>(qbf, kbf, vtb, abf);

    k_gemm_bt<<<dim3(512), dim3(256), 0, stream>>>(abf, wall + 3 * WT, bo,
                                                   (float*)d_out, 8192, 1024, 1024);
}